// Round 9
// baseline (127.725 us; speedup 1.0000x reference)
//
#include <hip/hip_runtime.h>
#include <math.h>

#define NBATCH 8192
#define NNEI 256
#define NROLE 3
#define NHID 32
#define NDIM 6
#define SSTRIDE 16  // floats; 64B record stride
#define BPB 4       // batches per block (grid = NBATCH/BPB)

typedef float v2f __attribute__((ext_vector_type(2)));
typedef unsigned long long ull;

// Compiler-fenced lgkm-only barrier (CK "block_sync_lds" idiom): unlike
// __syncthreads(), does NOT drain vmcnt — global prefetch loads stay in
// flight across the barrier. LDS producer/consumer only needs lgkmcnt(0).
// imm 0xC07F: vmcnt=63 (bits[3:0]=15,[15:14]=3), expcnt=7, lgkmcnt=0.
__device__ __forceinline__ void barrier_lds_only() {
  __asm__ __volatile__("" ::: "memory");
  __builtin_amdgcn_s_waitcnt(0xC07F);
  __builtin_amdgcn_s_barrier();
  __asm__ __volatile__("" ::: "memory");
}

// MLP score via packed-f32 pairs (v_pk_fma_f32): Linear(6,32)->ReLU->Linear(32,1).
// Weight pointers MUST be wave-uniform (readfirstlane'd role) so weight reads
// stay s_load scalar traffic — R5 showed losing this costs 4x.
__device__ __forceinline__ float mlp_score(const float x0, const float x1,
                                           const float x2, const float x3,
                                           const float x4, const float x5,
                                           const float* __restrict__ w1,
                                           const float* __restrict__ bb,
                                           const float* __restrict__ w2,
                                           const float b2v) {
  const float x[NDIM] = {x0, x1, x2, x3, x4, x5};
  v2f ac0 = {0.f, 0.f}, ac1 = {0.f, 0.f}, ac2 = {0.f, 0.f}, ac3 = {0.f, 0.f};
#pragma unroll
  for (int h = 0; h < NHID; h += 8) {
    v2f a0 = *(const v2f*)(bb + h + 0);
    v2f a1 = *(const v2f*)(bb + h + 2);
    v2f a2 = *(const v2f*)(bb + h + 4);
    v2f a3 = *(const v2f*)(bb + h + 6);
#pragma unroll
    for (int d = 0; d < NDIM; ++d) {
      const float xv = x[d];
      const v2f xv2 = {xv, xv};
      const float* wc = w1 + d * NHID + h;  // uniform addr -> s_load
      a0 += xv2 * (*(const v2f*)(wc + 0));  // -ffp-contract -> v_pk_fma_f32
      a1 += xv2 * (*(const v2f*)(wc + 2));
      a2 += xv2 * (*(const v2f*)(wc + 4));
      a3 += xv2 * (*(const v2f*)(wc + 6));
    }
    a0.x = fmaxf(a0.x, 0.f); a0.y = fmaxf(a0.y, 0.f);
    a1.x = fmaxf(a1.x, 0.f); a1.y = fmaxf(a1.y, 0.f);
    a2.x = fmaxf(a2.x, 0.f); a2.y = fmaxf(a2.y, 0.f);
    a3.x = fmaxf(a3.x, 0.f); a3.y = fmaxf(a3.y, 0.f);
    ac0 += a0 * (*(const v2f*)(w2 + h + 0));
    ac1 += a1 * (*(const v2f*)(w2 + h + 2));
    ac2 += a2 * (*(const v2f*)(w2 + h + 4));
    ac3 += a3 * (*(const v2f*)(w2 + h + 6));
  }
  const v2f st = (ac0 + ac1) + (ac2 + ac3);
  return b2v + st.x + st.y;
}

// Softmax max-subtraction cancels exactly in mf = sum(e*tw*v)/sum(e*tw)
// (exp(-m) divides out; only the 1e-8 epsilons break it, ~1e-10 relative;
// scores are O(1..12) so exp cannot overflow) — so we skip the max chain.
__global__ __launch_bounds__(256) void hmf_main(
    const float* __restrict__ states,
    const int* __restrict__ roles,
    const int* __restrict__ maskp,   // bool arrives as int32
    const float* __restrict__ trust,
    const float* __restrict__ W1,    // [R][D][H]
    const float* __restrict__ b1,    // [R][H]
    const float* __restrict__ W2,    // [R][H]
    const float* __restrict__ b2g,   // [R]
    float* __restrict__ out) {
  const int tid = threadIdx.x;
  const int wave = tid >> 6;
  const int lane = tid & 63;
  const int b0 = blockIdx.x * BPB;

  __shared__ float ssort[NNEI * SSTRIDE];  // 16 KB; wave w owns slots [64w,64w+64)
  __shared__ int scnt[12];                 // [w*3+r]

  // ---- prefetch batch b0 ----
  size_t rowb = (size_t)b0 * NNEI;
  int n_role = roles[rowb + tid];
  int n_mask = maskp[rowb + tid];
  float n_tw = trust[rowb + tid];
  const float* sp = states + rowb * NDIM + (size_t)tid * NDIM;
  float2 n_sA = *(const float2*)(sp);
  float2 n_sB = *(const float2*)(sp + 2);
  float2 n_sC = *(const float2*)(sp + 4);

#pragma unroll 1  // rolled: ONE copy of the body (R3 showed 8 copies bloat)
  for (int i = 0; i < BPB; ++i) {
    // rotate prefetched -> current
    const int myrole = n_role;
    const int mymask = n_mask;
    const float mytw = n_tw;
    const float2 sA = n_sA;
    const float2 sB = n_sB;
    const float2 sC = n_sC;

    // ---- issue prefetch for next batch (stays in flight across barriers) ----
    const int inext = (i + 1 < BPB) ? (i + 1) : i;  // clamp: redundant last load
    rowb = (size_t)(b0 + inext) * NNEI;
    n_role = roles[rowb + tid];
    n_mask = maskp[rowb + tid];
    n_tw = trust[rowb + tid];
    const float* spn = states + rowb * NDIM + (size_t)tid * NDIM;
    n_sA = *(const float2*)(spn);
    n_sB = *(const float2*)(spn + 2);
    n_sC = *(const float2*)(spn + 4);

    // ---- phase 1: ballots + intra-wave role-sorted scatter ----
    const bool active = (mymask != 0);
    const ull bal0 = __ballot(active && (myrole == 0));
    const ull bal1 = __ballot(active && (myrole == 1));
    const ull bal2 = __ballot(active && (myrole == 2));
    const int c0 = __popcll(bal0);
    const int c1 = __popcll(bal1);
    const int c2 = __popcll(bal2);
    if (lane < 3) scnt[wave * 3 + lane] = (lane == 0) ? c0 : (lane == 1) ? c1 : c2;

    if (active) {
      const ull mybal = (myrole == 0) ? bal0 : (myrole == 1) ? bal1 : bal2;
      const int rank = __popcll(mybal & ((1ull << lane) - 1ull));
      const int pre = ((myrole >= 1) ? c0 : 0) + ((myrole >= 2) ? c1 : 0);
      const int pos = wave * 64 + pre + rank;  // wave-private region
      float* dst = ssort + pos * SSTRIDE;
      *(float4*)dst = make_float4(sA.x, sA.y, sB.x, sB.y);
      *(float2*)(dst + 4) = make_float2(sC.x, sC.y);
      dst[6] = mytw;
    }
    barrier_lds_only();  // scatter visible; prefetch vmcnt NOT drained

    // ---- phase 3: wave r handles role r across the 4 wave-segments ----
    if (wave < 3) {
      const int r = __builtin_amdgcn_readfirstlane(wave);
      int cwv[4], prw[4];
#pragma unroll
      for (int w = 0; w < 4; ++w) {
        const int a0 = scnt[w * 3 + 0];
        const int a1 = scnt[w * 3 + 1];
        const int a2 = scnt[w * 3 + 2];
        const int cv = (r == 0) ? a0 : (r == 1) ? a1 : a2;
        const int pv = ((r >= 1) ? a0 : 0) + ((r >= 2) ? a1 : 0);
        cwv[w] = __builtin_amdgcn_readfirstlane(cv);
        prw[w] = __builtin_amdgcn_readfirstlane(pv);
      }
      const int acc0 = cwv[0];
      const int acc1 = acc0 + cwv[1];
      const int acc2 = acc1 + cwv[2];
      const int cnt = acc2 + cwv[3];

      const float* w1 = W1 + r * (NDIM * NHID);
      const float* bb = b1 + r * NHID;
      const float* w2 = W2 + r * NHID;
      const float b2v = b2g[r];

      float q0, q1, q2, q3, q4, q5, q6, q7;  // {Se, Set, Sd0..Sd5}

      if (cnt <= 64) {
        // ---- FAST PATH (P ≈ 1 - 1e-4): single chunk, static control flow ----
        const bool act = lane < cnt;
        const bool s1 = lane >= acc0;
        const bool s2 = lane >= acc1;
        const bool s3 = lane >= acc2;
        int sub = s1 ? acc0 : 0; sub = s2 ? acc1 : sub; sub = s3 ? acc2 : sub;
        int wb = s1 ? 64 : 0;    wb = s2 ? 128 : wb;    wb = s3 ? 192 : wb;
        int pr = s1 ? prw[1] : prw[0]; pr = s2 ? prw[2] : pr; pr = s3 ? prw[3] : pr;
        int pos = wb + pr + (lane - sub);
        pos = (pos > NNEI - 1) ? (NNEI - 1) : pos;  // inactive lanes may overrun
        const float* s = ssort + pos * SSTRIDE;
        float4 v4 = *(const float4*)s;
        float2 v2 = *(const float2*)(s + 4);
        float tw = s[6];
        if (!act) {  // select-gate: garbage slots may hold NaN
          v4 = make_float4(0.f, 0.f, 0.f, 0.f);
          v2 = make_float2(0.f, 0.f);
          tw = 0.f;
        }
        const float sc = mlp_score(v4.x, v4.y, v4.z, v4.w, v2.x, v2.y, w1, bb, w2, b2v);
        const float e = act ? __expf(sc) : 0.f;
        const float et = e * tw;
        q0 = e; q1 = et;
        q2 = et * v4.x; q3 = et * v4.y; q4 = et * v4.z;
        q5 = et * v4.w; q6 = et * v2.x; q7 = et * v2.y;
      } else {
        // ---- SLOW PATH (cold, ~3 lists in 24576): dynamic chunk loop ----
        q0 = q1 = q2 = q3 = q4 = q5 = q6 = q7 = 0.f;
        const int nch = (cnt + 63) >> 6;
        for (int c = 0; c < nch; ++c) {
          const int jj = c * 64 + lane;
          const bool act = jj < cnt;
          const bool s1 = jj >= acc0;
          const bool s2 = jj >= acc1;
          const bool s3 = jj >= acc2;
          int sub = s1 ? acc0 : 0; sub = s2 ? acc1 : sub; sub = s3 ? acc2 : sub;
          int wb = s1 ? 64 : 0;    wb = s2 ? 128 : wb;    wb = s3 ? 192 : wb;
          int pr = s1 ? prw[1] : prw[0]; pr = s2 ? prw[2] : pr; pr = s3 ? prw[3] : pr;
          int pos = wb + pr + (jj - sub);
          pos = (pos > NNEI - 1) ? (NNEI - 1) : pos;
          pos = (pos < 0) ? 0 : pos;
          const float* s = ssort + pos * SSTRIDE;
          float4 v4 = *(const float4*)s;
          float2 v2 = *(const float2*)(s + 4);
          float tw = s[6];
          if (!act) {
            v4 = make_float4(0.f, 0.f, 0.f, 0.f);
            v2 = make_float2(0.f, 0.f);
            tw = 0.f;
          }
          const float sc = mlp_score(v4.x, v4.y, v4.z, v4.w, v2.x, v2.y, w1, bb, w2, b2v);
          const float e = act ? __expf(sc) : 0.f;
          const float et = e * tw;
          q0 += e; q1 += et;
          q2 = fmaf(et, v4.x, q2); q3 = fmaf(et, v4.y, q3);
          q4 = fmaf(et, v4.z, q4); q5 = fmaf(et, v4.w, q5);
          q6 = fmaf(et, v2.x, q6); q7 = fmaf(et, v2.y, q7);
        }
      }

      // ---- reduction: 3 xor steps x8 (independent), select, 3 xor steps x1 ----
#pragma unroll
      for (int off = 1; off <= 4; off <<= 1) {
        q0 += __shfl_xor(q0, off); q1 += __shfl_xor(q1, off);
        q2 += __shfl_xor(q2, off); q3 += __shfl_xor(q3, off);
        q4 += __shfl_xor(q4, off); q5 += __shfl_xor(q5, off);
        q6 += __shfl_xor(q6, off); q7 += __shfl_xor(q7, off);
      }
      const int g = lane & 7;
      float myq = q0;
      myq = (g == 1) ? q1 : myq;
      myq = (g == 2) ? q2 : myq;
      myq = (g == 3) ? q3 : myq;
      myq = (g == 4) ? q4 : myq;
      myq = (g == 5) ? q5 : myq;
      myq = (g == 6) ? q6 : myq;
      myq = (g == 7) ? q7 : myq;
      myq += __shfl_xor(myq, 8);
      myq += __shfl_xor(myq, 16);
      myq += __shfl_xor(myq, 32);
      const float Se = __shfl(myq, 0);
      const float Set = __shfl(myq, 1);
      const float denom = Se + 1e-8f;
      const float ws = fmaxf(Set / denom, 1e-8f);
      if (lane >= 2 && lane < 8) {
        out[(size_t)(b0 + i) * (NROLE * NDIM) + r * NDIM + (lane - 2)] =
            (myq / denom) / ws;
      }
    }
    barrier_lds_only();  // protect ssort/scnt reuse by next iteration
  }
}

extern "C" void kernel_launch(void* const* d_in, const int* in_sizes, int n_in,
                              void* d_out, int out_size, void* d_ws, size_t ws_size,
                              hipStream_t stream) {
  const float* states = (const float*)d_in[0];
  const int* roles = (const int*)d_in[1];
  const int* maskp = (const int*)d_in[2];
  const float* trust = (const float*)d_in[3];
  const float* W1 = (const float*)d_in[4];
  const float* b1 = (const float*)d_in[5];
  const float* W2 = (const float*)d_in[6];
  const float* b2 = (const float*)d_in[7];
  float* out = (float*)d_out;

  hmf_main<<<NBATCH / BPB, 256, 0, stream>>>(states, roles, maskp, trust, W1, b1, W2, b2, out);
}

// Round 10
// 118.876 us; speedup vs baseline: 1.0744x; 1.0744x over previous
//
#include <hip/hip_runtime.h>
#include <math.h>

#define NBATCH 8192
#define NNEI 256
#define NROLE 3
#define NHID 32
#define NDIM 6
// 48B record stride: record p's b128 lands in 16B-bank-group (3p mod 8) — a
// perfect permutation over all 8 groups -> near-conflict-free for b128/b64/b32.
// (R9 measured stride 16 floats = 64B -> only 2 groups -> 1.7M conflict cycles.)
#define SSTRIDE 12

typedef float v2f __attribute__((ext_vector_type(2)));
typedef unsigned long long ull;

// Compiler-fenced lgkm-only barrier (CK "block_sync_lds" idiom): unlike
// __syncthreads(), does NOT drain vmcnt — any global loads stay in flight.
// imm 0xC07F: vmcnt=63, expcnt=7, lgkmcnt=0.
__device__ __forceinline__ void barrier_lds_only() {
  __asm__ __volatile__("" ::: "memory");
  __builtin_amdgcn_s_waitcnt(0xC07F);
  __builtin_amdgcn_s_barrier();
  __asm__ __volatile__("" ::: "memory");
}

// MLP score via packed-f32 pairs (v_pk_fma_f32): Linear(6,32)->ReLU->Linear(32,1).
// Weight pointers MUST be wave-uniform (readfirstlane'd role) so weight reads
// stay s_load scalar traffic — R5 showed losing this costs 4x.
__device__ __forceinline__ float mlp_score(const float x0, const float x1,
                                           const float x2, const float x3,
                                           const float x4, const float x5,
                                           const float* __restrict__ w1,
                                           const float* __restrict__ bb,
                                           const float* __restrict__ w2,
                                           const float b2v) {
  const float x[NDIM] = {x0, x1, x2, x3, x4, x5};
  v2f ac0 = {0.f, 0.f}, ac1 = {0.f, 0.f}, ac2 = {0.f, 0.f}, ac3 = {0.f, 0.f};
#pragma unroll
  for (int h = 0; h < NHID; h += 8) {
    v2f a0 = *(const v2f*)(bb + h + 0);
    v2f a1 = *(const v2f*)(bb + h + 2);
    v2f a2 = *(const v2f*)(bb + h + 4);
    v2f a3 = *(const v2f*)(bb + h + 6);
#pragma unroll
    for (int d = 0; d < NDIM; ++d) {
      const float xv = x[d];
      const v2f xv2 = {xv, xv};
      const float* wc = w1 + d * NHID + h;  // uniform addr -> s_load
      a0 += xv2 * (*(const v2f*)(wc + 0));  // -ffp-contract -> v_pk_fma_f32
      a1 += xv2 * (*(const v2f*)(wc + 2));
      a2 += xv2 * (*(const v2f*)(wc + 4));
      a3 += xv2 * (*(const v2f*)(wc + 6));
    }
    a0.x = fmaxf(a0.x, 0.f); a0.y = fmaxf(a0.y, 0.f);
    a1.x = fmaxf(a1.x, 0.f); a1.y = fmaxf(a1.y, 0.f);
    a2.x = fmaxf(a2.x, 0.f); a2.y = fmaxf(a2.y, 0.f);
    a3.x = fmaxf(a3.x, 0.f); a3.y = fmaxf(a3.y, 0.f);
    ac0 += a0 * (*(const v2f*)(w2 + h + 0));
    ac1 += a1 * (*(const v2f*)(w2 + h + 2));
    ac2 += a2 * (*(const v2f*)(w2 + h + 4));
    ac3 += a3 * (*(const v2f*)(w2 + h + 6));
  }
  const v2f st = (ac0 + ac1) + (ac2 + ac3);
  return b2v + st.x + st.y;
}

// Softmax max-subtraction cancels exactly in mf = sum(e*tw*v)/sum(e*tw)
// (exp(-m) divides out; only the 1e-8 epsilons break it, ~1e-10 relative;
// scores are O(1..12) so exp cannot overflow) — so we skip the max chain.
__global__ __launch_bounds__(256) void hmf_main(
    const float* __restrict__ states,
    const int* __restrict__ roles,
    const int* __restrict__ maskp,   // bool arrives as int32
    const float* __restrict__ trust,
    const float* __restrict__ W1,    // [R][D][H]
    const float* __restrict__ b1,    // [R][H]
    const float* __restrict__ W2,    // [R][H]
    const float* __restrict__ b2g,   // [R]
    float* __restrict__ out) {
  const int b = blockIdx.x;
  const int tid = threadIdx.x;
  const int wave = tid >> 6;
  const int lane = tid & 63;

  __shared__ float ssort[NNEI * SSTRIDE];  // 12 KB; wave w owns slots [64w,64w+64)
  __shared__ int scnt[12];                 // [w*3+r]

  // ---- phase 1: coalesced loads, per-role ballots, intra-wave sorted scatter ----
  const size_t rowb = (size_t)b * NNEI;
  const int myrole = roles[rowb + tid];
  const int mymask = maskp[rowb + tid];
  const float mytw = trust[rowb + tid];
  const float* sp = states + rowb * NDIM + (size_t)tid * NDIM;
  const float2 sA = *(const float2*)(sp);
  const float2 sB = *(const float2*)(sp + 2);
  const float2 sC = *(const float2*)(sp + 4);
  const bool active = (mymask != 0);

  const ull bal0 = __ballot(active && (myrole == 0));
  const ull bal1 = __ballot(active && (myrole == 1));
  const ull bal2 = __ballot(active && (myrole == 2));
  const int c0 = __popcll(bal0);
  const int c1 = __popcll(bal1);
  const int c2 = __popcll(bal2);
  if (lane < 3) scnt[wave * 3 + lane] = (lane == 0) ? c0 : (lane == 1) ? c1 : c2;

  if (active) {
    const ull mybal = (myrole == 0) ? bal0 : (myrole == 1) ? bal1 : bal2;
    const int rank = __popcll(mybal & ((1ull << lane) - 1ull));
    const int pre = ((myrole >= 1) ? c0 : 0) + ((myrole >= 2) ? c1 : 0);
    const int pos = wave * 64 + pre + rank;  // wave-private region
    float* dst = ssort + pos * SSTRIDE;
    *(float4*)dst = make_float4(sA.x, sA.y, sB.x, sB.y);
    *(float2*)(dst + 4) = make_float2(sC.x, sC.y);
    dst[6] = mytw;
  }
  barrier_lds_only();  // the ONLY barrier

  // ---- phase 3: wave r handles role r across the 4 wave-segments ----
  if (wave < 3) {
    const int r = __builtin_amdgcn_readfirstlane(wave);
    int cwv[4], prw[4];
#pragma unroll
    for (int w = 0; w < 4; ++w) {
      const int a0 = scnt[w * 3 + 0];
      const int a1 = scnt[w * 3 + 1];
      const int a2 = scnt[w * 3 + 2];
      const int cv = (r == 0) ? a0 : (r == 1) ? a1 : a2;
      const int pv = ((r >= 1) ? a0 : 0) + ((r >= 2) ? a1 : 0);
      cwv[w] = __builtin_amdgcn_readfirstlane(cv);
      prw[w] = __builtin_amdgcn_readfirstlane(pv);
    }
    const int acc0 = cwv[0];
    const int acc1 = acc0 + cwv[1];
    const int acc2 = acc1 + cwv[2];
    const int cnt = acc2 + cwv[3];

    const float* w1 = W1 + r * (NDIM * NHID);
    const float* bb = b1 + r * NHID;
    const float* w2 = W2 + r * NHID;
    const float b2v = b2g[r];

    float q0, q1, q2, q3, q4, q5, q6, q7;  // {Se, Set, Sd0..Sd5}

    if (cnt <= 64) {
      // ---- FAST PATH (P ≈ 1 - 1e-4): single chunk, static control flow ----
      const bool act = lane < cnt;
      const bool s1 = lane >= acc0;
      const bool s2 = lane >= acc1;
      const bool s3 = lane >= acc2;
      int sub = s1 ? acc0 : 0; sub = s2 ? acc1 : sub; sub = s3 ? acc2 : sub;
      int wb = s1 ? 64 : 0;    wb = s2 ? 128 : wb;    wb = s3 ? 192 : wb;
      int pr = s1 ? prw[1] : prw[0]; pr = s2 ? prw[2] : pr; pr = s3 ? prw[3] : pr;
      int pos = wb + pr + (lane - sub);
      pos = (pos > NNEI - 1) ? (NNEI - 1) : pos;  // inactive lanes may overrun
      const float* s = ssort + pos * SSTRIDE;
      float4 v4 = *(const float4*)s;
      float2 v2 = *(const float2*)(s + 4);
      float tw = s[6];
      if (!act) {  // select-gate: garbage slots may hold NaN
        v4 = make_float4(0.f, 0.f, 0.f, 0.f);
        v2 = make_float2(0.f, 0.f);
        tw = 0.f;
      }
      const float sc = mlp_score(v4.x, v4.y, v4.z, v4.w, v2.x, v2.y, w1, bb, w2, b2v);
      const float e = act ? __expf(sc) : 0.f;
      const float et = e * tw;
      q0 = e; q1 = et;
      q2 = et * v4.x; q3 = et * v4.y; q4 = et * v4.z;
      q5 = et * v4.w; q6 = et * v2.x; q7 = et * v2.y;
    } else {
      // ---- SLOW PATH (cold, ~3 lists in 24576): dynamic chunk loop ----
      q0 = q1 = q2 = q3 = q4 = q5 = q6 = q7 = 0.f;
      const int nch = (cnt + 63) >> 6;
      for (int c = 0; c < nch; ++c) {
        const int jj = c * 64 + lane;
        const bool act = jj < cnt;
        const bool s1 = jj >= acc0;
        const bool s2 = jj >= acc1;
        const bool s3 = jj >= acc2;
        int sub = s1 ? acc0 : 0; sub = s2 ? acc1 : sub; sub = s3 ? acc2 : sub;
        int wb = s1 ? 64 : 0;    wb = s2 ? 128 : wb;    wb = s3 ? 192 : wb;
        int pr = s1 ? prw[1] : prw[0]; pr = s2 ? prw[2] : pr; pr = s3 ? prw[3] : pr;
        int pos = wb + pr + (jj - sub);
        pos = (pos > NNEI - 1) ? (NNEI - 1) : pos;
        pos = (pos < 0) ? 0 : pos;
        const float* s = ssort + pos * SSTRIDE;
        float4 v4 = *(const float4*)s;
        float2 v2 = *(const float2*)(s + 4);
        float tw = s[6];
        if (!act) {
          v4 = make_float4(0.f, 0.f, 0.f, 0.f);
          v2 = make_float2(0.f, 0.f);
          tw = 0.f;
        }
        const float sc = mlp_score(v4.x, v4.y, v4.z, v4.w, v2.x, v2.y, w1, bb, w2, b2v);
        const float e = act ? __expf(sc) : 0.f;
        const float et = e * tw;
        q0 += e; q1 += et;
        q2 = fmaf(et, v4.x, q2); q3 = fmaf(et, v4.y, q3);
        q4 = fmaf(et, v4.z, q4); q5 = fmaf(et, v4.w, q5);
        q6 = fmaf(et, v2.x, q6); q7 = fmaf(et, v2.y, q7);
      }
    }

    // ---- reduction: 3 xor steps x8 (independent), select, 3 xor steps x1 ----
#pragma unroll
    for (int off = 1; off <= 4; off <<= 1) {
      q0 += __shfl_xor(q0, off); q1 += __shfl_xor(q1, off);
      q2 += __shfl_xor(q2, off); q3 += __shfl_xor(q3, off);
      q4 += __shfl_xor(q4, off); q5 += __shfl_xor(q5, off);
      q6 += __shfl_xor(q6, off); q7 += __shfl_xor(q7, off);
    }
    const int g = lane & 7;
    float myq = q0;
    myq = (g == 1) ? q1 : myq;
    myq = (g == 2) ? q2 : myq;
    myq = (g == 3) ? q3 : myq;
    myq = (g == 4) ? q4 : myq;
    myq = (g == 5) ? q5 : myq;
    myq = (g == 6) ? q6 : myq;
    myq = (g == 7) ? q7 : myq;
    myq += __shfl_xor(myq, 8);
    myq += __shfl_xor(myq, 16);
    myq += __shfl_xor(myq, 32);
    // lane i now holds the 64-lane total of quantity (i & 7)
    const float Se = __shfl(myq, 0);
    const float Set = __shfl(myq, 1);
    const float denom = Se + 1e-8f;
    const float ws = fmaxf(Set / denom, 1e-8f);
    if (lane >= 2 && lane < 8) {
      out[(size_t)b * (NROLE * NDIM) + r * NDIM + (lane - 2)] = (myq / denom) / ws;
    }
  }
}

extern "C" void kernel_launch(void* const* d_in, const int* in_sizes, int n_in,
                              void* d_out, int out_size, void* d_ws, size_t ws_size,
                              hipStream_t stream) {
  const float* states = (const float*)d_in[0];
  const int* roles = (const int*)d_in[1];
  const int* maskp = (const int*)d_in[2];
  const float* trust = (const float*)d_in[3];
  const float* W1 = (const float*)d_in[4];
  const float* b1 = (const float*)d_in[5];
  const float* W2 = (const float*)d_in[6];
  const float* b2 = (const float*)d_in[7];
  float* out = (float*)d_out;

  hmf_main<<<NBATCH, 256, 0, stream>>>(states, roles, maskp, trust, W1, b1, W2, b2, out);
}